// Round 17
// baseline (60.565 us; speedup 1.0000x reference)
//
#include <hip/hip_runtime.h>
#include <hip/hip_fp16.h>
#include <math.h>

#define B_ 16
#define F_ 256
#define T_ 2048
#define K_ 20
#define OUTK 21
#define NPAIR 10

typedef float v2f __attribute__((ext_vector_type(2)));

#if __has_builtin(__builtin_amdgcn_cvt_pk_f32_fp8) && __has_builtin(__builtin_amdgcn_cvt_pk_fp8_f32)
#define HW_FP8 1
#else
#define HW_FP8 0
#endif

#if !HW_FP8
// fallback e4m3 (OCP) decode/encode — only compiled if HW cvt builtins absent
__device__ __forceinline__ float dec_fp8(unsigned v) {
    unsigned s = (v >> 7) & 1, e = (v >> 3) & 15, m = v & 7;
    float r = e ? __uint_as_float(((e + 120u) << 23) | (m << 20))
                : (float)m * 0.001953125f;  // 2^-9
    return s ? -r : r;
}
__device__ __forceinline__ unsigned enc_fp8(float x) {
    unsigned bits = __float_as_uint(x);
    unsigned s = bits >> 31;
    unsigned a = bits & 0x7fffffffu;
    float ax = __uint_as_float(a);
    unsigned r;
    if (ax < 0.015625f) {                      // subnormal (< 2^-6)
        r = (unsigned)(int)(ax * 512.f + 0.5f);
    } else {
        int e = (int)(a >> 23) - 127;
        unsigned m = a & 0x7fffffu;
        unsigned keep = m >> 20, rest = m & 0xFFFFFu;
        keep += (rest > 0x80000u) || (rest == 0x80000u && (keep & 1));
        if (keep == 8) { keep = 0; ++e; }
        r = ((unsigned)(e + 7) << 3) | keep;
    }
    return (s << 7) | r;
}
#endif

__device__ __forceinline__ unsigned pack_fp8x4(float a0, float a1, float a2, float a3) {
#if HW_FP8
    int u = 0;
    u = __builtin_amdgcn_cvt_pk_fp8_f32(a0, a1, u, false);
    u = __builtin_amdgcn_cvt_pk_fp8_f32(a2, a3, u, true);
    return (unsigned)u;
#else
    return enc_fp8(a0) | (enc_fp8(a1) << 8) | (enc_fp8(a2) << 16) | (enc_fp8(a3) << 24);
#endif
}
template <bool HI>
__device__ __forceinline__ v2f unpk_fp8(unsigned u) {
#if HW_FP8
    return __builtin_amdgcn_cvt_pk_f32_fp8((int)u, HI);
#else
    v2f r; unsigned x = HI ? (u >> 16) : u;
    r[0] = dec_fp8(x & 0xFF); r[1] = dec_fp8((x >> 8) & 0xFF);
    return r;
#endif
}

// Prep: identical to r16.
__global__ __launch_bounds__(256) void prep_kernel(
    const float* __restrict__ z, const float* __restrict__ c,
    unsigned char* __restrict__ zf8, unsigned char* __restrict__ cf8)
{
    __shared__ float tile[256][33];  // 256 f x 32 t, +1 pad
    __shared__ float ps[32][9];      // 8 partial sums per column, +1 pad
    __shared__ float sc[32];         // per-column 1/norm
    int which = blockIdx.z;
    unsigned char* dst = which ? cf8 : zf8;

    int b  = blockIdx.y;
    int t0 = blockIdx.x * 32;

    if (which == 0) {
        const float* zb = z + (size_t)b * F_ * T_ + t0;
        int q  = threadIdx.x & 7;
        int fo = threadIdx.x >> 3;
#pragma unroll
        for (int i = 0; i < 8; ++i) {
            int f = i * 32 + fo;
            float4 v = *(const float4*)(zb + (size_t)f * T_ + 4 * q);
            tile[f][4 * q + 0] = v.x;
            tile[f][4 * q + 1] = v.y;
            tile[f][4 * q + 2] = v.z;
            tile[f][4 * q + 3] = v.w;
        }
    } else {
        const float* cb = c + (size_t)b * F_ * (T_ + 1);
        int tl = threadIdx.x & 31;
        int fl = threadIdx.x >> 5;
#pragma unroll
        for (int i = 0; i < 32; ++i) {
            int f = i * 8 + fl;
            tile[f][tl] = cb[(size_t)f * (T_ + 1) + (t0 + tl + 1)];
        }
    }
    __syncthreads();
    {
        int col = threadIdx.x & 31, oct = threadIdx.x >> 5;
        float s = 0.f;
#pragma unroll 8
        for (int qq = 0; qq < 32; ++qq) {
            float v = tile[oct * 32 + qq][col];
            s = fmaf(v, v, s);
        }
        ps[col][oct] = s;
    }
    __syncthreads();
    if (threadIdx.x < 32) {
        float s = 0.f;
#pragma unroll
        for (int o = 0; o < 8; ++o) s += ps[threadIdx.x][o];
        float n = sqrtf(s);
        sc[threadIdx.x] = (n > 0.f) ? (1.0f / n) : 0.f;
    }
    __syncthreads();
    {
        int j = threadIdx.x & 63, r4 = threadIdx.x >> 6;
#pragma unroll
        for (int it = 0; it < 8; ++it) {
            int row = it * 4 + r4;
            float s = sc[row];
            unsigned u = pack_fp8x4(tile[2 * j][row] * s, tile[2 * j + 1][row] * s,
                                    tile[2 * j + 128][row] * s, tile[2 * j + 129][row] * s);
            ((unsigned*)(dst + ((size_t)b * T_ + t0 + row) * F_))[j] = u;
        }
    }
}

// Sum within each 32-lane half (pure VALU DPP). Valid in lane 31 (lo) / 63 (hi).
__device__ __forceinline__ float dpp_half_sum(float x) {
    x += __int_as_float(__builtin_amdgcn_mov_dpp(__float_as_int(x), 0x111, 0xF, 0xF, true)); // row_shr:1
    x += __int_as_float(__builtin_amdgcn_mov_dpp(__float_as_int(x), 0x112, 0xF, 0xF, true)); // row_shr:2
    x += __int_as_float(__builtin_amdgcn_mov_dpp(__float_as_int(x), 0x114, 0xF, 0xF, true)); // row_shr:4
    x += __int_as_float(__builtin_amdgcn_mov_dpp(__float_as_int(x), 0x118, 0xF, 0xF, true)); // row_shr:8
    x += __int_as_float(__builtin_amdgcn_mov_dpp(__float_as_int(x), 0x142, 0xF, 0xF, true)); // row_bcast:15
    return x;
}

// Sim: identical to r16.
__global__ __launch_bounds__(256, 8) void sim_kernel(
    const unsigned char* __restrict__ zf8, const unsigned char* __restrict__ cf8,
    const int* __restrict__ inds, float* __restrict__ out)
{
    __shared__ float sd[128];                         // 4 waves x 32 slots
    int i = blockIdx.x;                               // 8192 blocks, 4 waves each
    int b = (i & 7) | ((i >= 4096) ? 8 : 0);          // batch b on XCD b&7 (L2-resident tables)
    int wid = threadIdx.x >> 6;
    int t = (((i >> 3) & 511) << 2) + wid;
    int lane = threadIdx.x & 63;
    int hl = lane & 31;                               // pos within half
    int hi = lane >> 5;                               // which half
    int bt = __builtin_amdgcn_readfirstlane((b << 11) + t);

    const int* myinds = inds + bt * K_;
    int idxv = myinds[(lane < K_) ? lane : 0];        // lane k holds inds[k]

    uint2 zv8 = ((const uint2*)(zf8 + (size_t)bt * F_))[hl];   // own z row (fp8)
    uint2 cv8 = ((const uint2*)(cf8 + (size_t)bt * F_))[hl];   // own c row (fp8)

    const char* tbl8 = (const char*)zf8;
    unsigned zbase8  = (unsigned)(b << 11) * 256u;
    unsigned laneoff = (unsigned)hl * 8u;

    uint2 tv[NPAIR];
#pragma unroll
    for (int p = 0; p < NPAIR; ++p) {
        unsigned ilo = (unsigned)__builtin_amdgcn_readlane(idxv, 2 * p);
        unsigned ihi = (unsigned)__builtin_amdgcn_readlane(idxv, 2 * p + 1);
        unsigned off = zbase8 + (hi ? ihi : ilo) * 256u + laneoff;
        tv[p] = *(const uint2*)(tbl8 + off);
    }

    __builtin_amdgcn_sched_barrier(0);

    float zf[8];
    {
        v2f a01 = unpk_fp8<false>(zv8.x), a23 = unpk_fp8<true>(zv8.x);
        v2f a45 = unpk_fp8<false>(zv8.y), a67 = unpk_fp8<true>(zv8.y);
        zf[0] = a01[0]; zf[1] = a01[1]; zf[2] = a23[0]; zf[3] = a23[1];
        zf[4] = a45[0]; zf[5] = a45[1]; zf[6] = a67[0]; zf[7] = a67[1];
    }

    float dc;
    {
        v2f c01 = unpk_fp8<false>(cv8.x), c23 = unpk_fp8<true>(cv8.x);
        v2f c45 = unpk_fp8<false>(cv8.y), c67 = unpk_fp8<true>(cv8.y);
        float d = zf[0] * c01[0];
        d = fmaf(zf[1], c01[1], d);
        d = fmaf(zf[2], c23[0], d);
        d = fmaf(zf[3], c23[1], d);
        d = fmaf(zf[4], c45[0], d);
        d = fmaf(zf[5], c45[1], d);
        d = fmaf(zf[6], c67[0], d);
        d = fmaf(zf[7], c67[1], d);
        dc = d;
    }

    float dz[NPAIR];
#pragma unroll
    for (int p = 0; p < NPAIR; ++p) {
        v2f t01 = unpk_fp8<false>(tv[p].x), t23 = unpk_fp8<true>(tv[p].x);
        v2f t45 = unpk_fp8<false>(tv[p].y), t67 = unpk_fp8<true>(tv[p].y);
        float d = zf[0] * t01[0];
        d = fmaf(zf[1], t01[1], d);
        d = fmaf(zf[2], t23[0], d);
        d = fmaf(zf[3], t23[1], d);
        d = fmaf(zf[4], t45[0], d);
        d = fmaf(zf[5], t45[1], d);
        d = fmaf(zf[6], t67[0], d);
        d = fmaf(zf[7], t67[1], d);
        dz[p] = d;
    }

    unsigned mb = 0;
#pragma unroll
    for (int p = 0; p < NPAIR; ++p) {
        unsigned long long ball = __ballot(tv[p].x == cv8.x);
        unsigned blo = (unsigned)ball, bhi = (unsigned)(ball >> 32);
        if (blo == 0xFFFFFFFFu || bhi == 0xFFFFFFFFu) {
            bool full = (tv[p].x == cv8.x) && (tv[p].y == cv8.y);
            unsigned long long b2 = __ballot(full);
            if ((unsigned)b2 == 0xFFFFFFFFu)          mb |= 1u << (1 + 2 * p);
            if ((unsigned)(b2 >> 32) == 0xFFFFFFFFu)  mb |= 1u << (2 + 2 * p);
        }
    }

    dc = dpp_half_sum(dc);
#pragma unroll
    for (int p = 0; p < NPAIR; ++p) dz[p] = dpp_half_sum(dz[p]);

    if (hl == 31) {
        if (hi == 0) sd[wid * 32] = dc;
#pragma unroll
        for (int p = 0; p < NPAIR; ++p) sd[wid * 32 + 1 + 2 * p + hi] = dz[p];
    }

    if (lane < OUTK) {
        float v = sd[wid * 32 + lane] * 2.0f;         // / TEMP, TEMP = 0.5
        if ((mb >> lane) & 1u) v = -INFINITY;
        out[(size_t)bt * OUTK + lane] = v;
    }
}

extern "C" void kernel_launch(void* const* d_in, const int* in_sizes, int n_in,
                              void* d_out, int out_size, void* d_ws, size_t ws_size,
                              hipStream_t stream)
{
    const float* z    = (const float*)d_in[0];
    const float* c    = (const float*)d_in[1];
    const int*   inds = (const int*)d_in[2];
    float* out = (float*)d_out;

    char* ws = (char*)d_ws;
    size_t f8_bytes = (size_t)B_ * T_ * F_;                    // 8 MB
    unsigned char* zf8 = (unsigned char*)ws;
    unsigned char* cf8 = (unsigned char*)(ws + f8_bytes);

    dim3 tb(256), tg(T_ / 32, B_, 2);
    prep_kernel<<<tg, tb, 0, stream>>>(z, c, zf8, cf8);
    // DIAGNOSTIC (r17): sim launched TWICE (idempotent — identical output).
    // delta vs r16's 42.4 us == sim's true duration, resolving the
    // prep/sim decomposition that the memset-polluted profile hides.
    sim_kernel<<<dim3(B_ * T_ / 4), dim3(256), 0, stream>>>(zf8, cf8, inds, out);
    sim_kernel<<<dim3(B_ * T_ / 4), dim3(256), 0, stream>>>(zf8, cf8, inds, out);
}

// Round 18
// 42.188 us; speedup vs baseline: 1.4356x; 1.4356x over previous
//
#include <hip/hip_runtime.h>
#include <hip/hip_fp16.h>
#include <math.h>

#define B_ 16
#define F_ 256
#define T_ 2048
#define K_ 20
#define OUTK 21
#define NPAIR 10

typedef float v2f __attribute__((ext_vector_type(2)));

#if __has_builtin(__builtin_amdgcn_cvt_pk_f32_fp8) && __has_builtin(__builtin_amdgcn_cvt_pk_fp8_f32)
#define HW_FP8 1
#else
#define HW_FP8 0
#endif

#if !HW_FP8
// fallback e4m3 (OCP) decode/encode — only compiled if HW cvt builtins absent
__device__ __forceinline__ float dec_fp8(unsigned v) {
    unsigned s = (v >> 7) & 1, e = (v >> 3) & 15, m = v & 7;
    float r = e ? __uint_as_float(((e + 120u) << 23) | (m << 20))
                : (float)m * 0.001953125f;  // 2^-9
    return s ? -r : r;
}
__device__ __forceinline__ unsigned enc_fp8(float x) {
    unsigned bits = __float_as_uint(x);
    unsigned s = bits >> 31;
    unsigned a = bits & 0x7fffffffu;
    float ax = __uint_as_float(a);
    unsigned r;
    if (ax < 0.015625f) {                      // subnormal (< 2^-6)
        r = (unsigned)(int)(ax * 512.f + 0.5f);
    } else {
        int e = (int)(a >> 23) - 127;
        unsigned m = a & 0x7fffffu;
        unsigned keep = m >> 20, rest = m & 0xFFFFFu;
        keep += (rest > 0x80000u) || (rest == 0x80000u && (keep & 1));
        if (keep == 8) { keep = 0; ++e; }
        r = ((unsigned)(e + 7) << 3) | keep;
    }
    return (s << 7) | r;
}
#endif

__device__ __forceinline__ unsigned pack_fp8x4(float a0, float a1, float a2, float a3) {
#if HW_FP8
    int u = 0;
    u = __builtin_amdgcn_cvt_pk_fp8_f32(a0, a1, u, false);
    u = __builtin_amdgcn_cvt_pk_fp8_f32(a2, a3, u, true);
    return (unsigned)u;
#else
    return enc_fp8(a0) | (enc_fp8(a1) << 8) | (enc_fp8(a2) << 16) | (enc_fp8(a3) << 24);
#endif
}
template <bool HI>
__device__ __forceinline__ v2f unpk_fp8(unsigned u) {
#if HW_FP8
    return __builtin_amdgcn_cvt_pk_f32_fp8((int)u, HI);
#else
    v2f r; unsigned x = HI ? (u >> 16) : u;
    r[0] = dec_fp8(x & 0xFF); r[1] = dec_fp8((x >> 8) & 0xFF);
    return r;
#endif
}

// Prep: identical to r16 (measured ~24 us ~= its 144 MB HBM roofline).
__global__ __launch_bounds__(256) void prep_kernel(
    const float* __restrict__ z, const float* __restrict__ c,
    unsigned char* __restrict__ zf8, unsigned char* __restrict__ cf8)
{
    __shared__ float tile[256][33];  // 256 f x 32 t, +1 pad
    __shared__ float ps[32][9];      // 8 partial sums per column, +1 pad
    __shared__ float sc[32];         // per-column 1/norm
    int which = blockIdx.z;
    unsigned char* dst = which ? cf8 : zf8;

    int b  = blockIdx.y;
    int t0 = blockIdx.x * 32;

    if (which == 0) {
        const float* zb = z + (size_t)b * F_ * T_ + t0;
        int q  = threadIdx.x & 7;
        int fo = threadIdx.x >> 3;
#pragma unroll
        for (int i = 0; i < 8; ++i) {
            int f = i * 32 + fo;
            float4 v = *(const float4*)(zb + (size_t)f * T_ + 4 * q);
            tile[f][4 * q + 0] = v.x;
            tile[f][4 * q + 1] = v.y;
            tile[f][4 * q + 2] = v.z;
            tile[f][4 * q + 3] = v.w;
        }
    } else {
        const float* cb = c + (size_t)b * F_ * (T_ + 1);
        int tl = threadIdx.x & 31;
        int fl = threadIdx.x >> 5;
#pragma unroll
        for (int i = 0; i < 32; ++i) {
            int f = i * 8 + fl;
            tile[f][tl] = cb[(size_t)f * (T_ + 1) + (t0 + tl + 1)];
        }
    }
    __syncthreads();
    {
        int col = threadIdx.x & 31, oct = threadIdx.x >> 5;
        float s = 0.f;
#pragma unroll 8
        for (int qq = 0; qq < 32; ++qq) {
            float v = tile[oct * 32 + qq][col];
            s = fmaf(v, v, s);
        }
        ps[col][oct] = s;
    }
    __syncthreads();
    if (threadIdx.x < 32) {
        float s = 0.f;
#pragma unroll
        for (int o = 0; o < 8; ++o) s += ps[threadIdx.x][o];
        float n = sqrtf(s);
        sc[threadIdx.x] = (n > 0.f) ? (1.0f / n) : 0.f;
    }
    __syncthreads();
    {
        int j = threadIdx.x & 63, r4 = threadIdx.x >> 6;
#pragma unroll
        for (int it = 0; it < 8; ++it) {
            int row = it * 4 + r4;
            float s = sc[row];
            unsigned u = pack_fp8x4(tile[2 * j][row] * s, tile[2 * j + 1][row] * s,
                                    tile[2 * j + 128][row] * s, tile[2 * j + 129][row] * s);
            ((unsigned*)(dst + ((size_t)b * T_ + t0 + row) * F_))[j] = u;
        }
    }
}

// Sum within each 32-lane half (pure VALU DPP). Valid in lane 31 (lo) / 63 (hi).
__device__ __forceinline__ float dpp_half_sum(float x) {
    x += __int_as_float(__builtin_amdgcn_mov_dpp(__float_as_int(x), 0x111, 0xF, 0xF, true)); // row_shr:1
    x += __int_as_float(__builtin_amdgcn_mov_dpp(__float_as_int(x), 0x112, 0xF, 0xF, true)); // row_shr:2
    x += __int_as_float(__builtin_amdgcn_mov_dpp(__float_as_int(x), 0x114, 0xF, 0xF, true)); // row_shr:4
    x += __int_as_float(__builtin_amdgcn_mov_dpp(__float_as_int(x), 0x118, 0xF, 0xF, true)); // row_shr:8
    x += __int_as_float(__builtin_amdgcn_mov_dpp(__float_as_int(x), 0x142, 0xF, 0xF, true)); // row_bcast:15
    return x;
}

#define TV_LOADS(S) \
    uint2 tv##S[NPAIR]; \
    _Pragma("unroll") \
    for (int p = 0; p < NPAIR; ++p) { \
        unsigned ilo = (unsigned)__builtin_amdgcn_readlane(idxv##S, 2 * p); \
        unsigned ihi = (unsigned)__builtin_amdgcn_readlane(idxv##S, 2 * p + 1); \
        unsigned off = zbase8 + (hi ? ihi : ilo) * 256u + laneoff; \
        tv##S[p] = *(const uint2*)(tbl8 + off); \
    }

#define SIM_COMPUTE(S, tsel) \
    { \
        float zfv[8]; \
        { \
            v2f a01 = unpk_fp8<false>(zv8##S.x), a23 = unpk_fp8<true>(zv8##S.x); \
            v2f a45 = unpk_fp8<false>(zv8##S.y), a67 = unpk_fp8<true>(zv8##S.y); \
            zfv[0] = a01[0]; zfv[1] = a01[1]; zfv[2] = a23[0]; zfv[3] = a23[1]; \
            zfv[4] = a45[0]; zfv[5] = a45[1]; zfv[6] = a67[0]; zfv[7] = a67[1]; \
        } \
        float dc; \
        { \
            v2f c01 = unpk_fp8<false>(cv8##S.x), c23 = unpk_fp8<true>(cv8##S.x); \
            v2f c45 = unpk_fp8<false>(cv8##S.y), c67 = unpk_fp8<true>(cv8##S.y); \
            float d = zfv[0] * c01[0]; \
            d = fmaf(zfv[1], c01[1], d); d = fmaf(zfv[2], c23[0], d); \
            d = fmaf(zfv[3], c23[1], d); d = fmaf(zfv[4], c45[0], d); \
            d = fmaf(zfv[5], c45[1], d); d = fmaf(zfv[6], c67[0], d); \
            d = fmaf(zfv[7], c67[1], d); \
            dc = d; \
        } \
        float dz[NPAIR]; \
        _Pragma("unroll") \
        for (int p = 0; p < NPAIR; ++p) { \
            v2f t01 = unpk_fp8<false>(tv##S[p].x), t23 = unpk_fp8<true>(tv##S[p].x); \
            v2f t45 = unpk_fp8<false>(tv##S[p].y), t67 = unpk_fp8<true>(tv##S[p].y); \
            float d = zfv[0] * t01[0]; \
            d = fmaf(zfv[1], t01[1], d); d = fmaf(zfv[2], t23[0], d); \
            d = fmaf(zfv[3], t23[1], d); d = fmaf(zfv[4], t45[0], d); \
            d = fmaf(zfv[5], t45[1], d); d = fmaf(zfv[6], t67[0], d); \
            d = fmaf(zfv[7], t67[1], d); \
            dz[p] = d; \
        } \
        unsigned mb = 0; \
        _Pragma("unroll") \
        for (int p = 0; p < NPAIR; ++p) { \
            unsigned long long ball = __ballot(tv##S[p].x == cv8##S.x); \
            unsigned blo = (unsigned)ball, bhi = (unsigned)(ball >> 32); \
            if (blo == 0xFFFFFFFFu || bhi == 0xFFFFFFFFu) { \
                bool full = (tv##S[p].x == cv8##S.x) && (tv##S[p].y == cv8##S.y); \
                unsigned long long b2 = __ballot(full); \
                if ((unsigned)b2 == 0xFFFFFFFFu)          mb |= 1u << (1 + 2 * p); \
                if ((unsigned)(b2 >> 32) == 0xFFFFFFFFu)  mb |= 1u << (2 + 2 * p); \
            } \
        } \
        dc = dpp_half_sum(dc); \
        _Pragma("unroll") \
        for (int p = 0; p < NPAIR; ++p) dz[p] = dpp_half_sum(dz[p]); \
        if (hl == 31) { \
            if (hi == 0) sd[wid * 64 + (tsel) * 32] = dc; \
            _Pragma("unroll") \
            for (int p = 0; p < NPAIR; ++p) sd[wid * 64 + (tsel) * 32 + 1 + 2 * p + hi] = dz[p]; \
        } \
        if (lane < OUTK) { \
            float v = sd[wid * 64 + (tsel) * 32 + lane] * 2.0f; \
            if ((mb >> lane) & 1u) v = -INFINITY; \
            out[(size_t)bt##S * OUTK + lane] = v; \
        } \
    }

// One 64-lane wave per TWO (b,t) rows (t and t+1024). fp8 state is small
// (tv 20 VGPR/t) so 2-t fits ~80 VGPR without the r10 occupancy loss.
// All 26 loads (2 idx, 4 own-row, 20 gather) issue before one sched_barrier:
// the idx-load latency head amortizes over 2 t.
__global__ __launch_bounds__(256, 6) void sim_kernel(
    const unsigned char* __restrict__ zf8, const unsigned char* __restrict__ cf8,
    const int* __restrict__ inds, float* __restrict__ out)
{
    __shared__ float sd[256];                         // 4 waves x 2 t x 32 slots
    int i = blockIdx.x;                               // 4096 blocks, 4 waves each
    int b = (i & 7) | ((i >= 2048) ? 8 : 0);          // batch b on XCD b&7 (L2-resident tables)
    int wid = threadIdx.x >> 6;
    int lane = threadIdx.x & 63;
    int hl = lane & 31;                               // pos within half
    int hi = lane >> 5;                               // which half
    int tA = (((i >> 3) & 255) << 2) + wid;
    int btA = __builtin_amdgcn_readfirstlane((b << 11) + tA);
    int btB = btA + 1024;

    // idx loads first (the dependency heads) — both in flight together
    int idxvA = (inds + btA * K_)[(lane < K_) ? lane : 0];
    int idxvB = (inds + btB * K_)[(lane < K_) ? lane : 0];

    // own rows (independent of idx)
    uint2 zv8A = ((const uint2*)(zf8 + (size_t)btA * F_))[hl];
    uint2 cv8A = ((const uint2*)(cf8 + (size_t)btA * F_))[hl];
    uint2 zv8B = ((const uint2*)(zf8 + (size_t)btB * F_))[hl];
    uint2 cv8B = ((const uint2*)(cf8 + (size_t)btB * F_))[hl];

    const char* tbl8 = (const char*)zf8;
    unsigned zbase8  = (unsigned)(b << 11) * 256u;
    unsigned laneoff = (unsigned)hl * 8u;

    // gathers: A then B (B's issue only waits on idxvB, already in flight)
    TV_LOADS(A)
    TV_LOADS(B)

    // hard scheduler fence: all 26 loads stay issued up-front
    __builtin_amdgcn_sched_barrier(0);

    SIM_COMPUTE(A, 0)
    SIM_COMPUTE(B, 1)
}

extern "C" void kernel_launch(void* const* d_in, const int* in_sizes, int n_in,
                              void* d_out, int out_size, void* d_ws, size_t ws_size,
                              hipStream_t stream)
{
    const float* z    = (const float*)d_in[0];
    const float* c    = (const float*)d_in[1];
    const int*   inds = (const int*)d_in[2];
    float* out = (float*)d_out;

    char* ws = (char*)d_ws;
    size_t f8_bytes = (size_t)B_ * T_ * F_;                    // 8 MB
    unsigned char* zf8 = (unsigned char*)ws;
    unsigned char* cf8 = (unsigned char*)(ws + f8_bytes);

    dim3 tb(256), tg(T_ / 32, B_, 2);
    prep_kernel<<<tg, tb, 0, stream>>>(z, c, zf8, cf8);
    sim_kernel<<<dim3(B_ * T_ / 8), dim3(256), 0, stream>>>(zf8, cf8, inds, out);
}